// Round 1
// baseline (2723.400 us; speedup 1.0000x reference)
//
#include <hip/hip_runtime.h>
#include <hip/hip_bf16.h>

#define BM 128
#define BN 128
#define BK 8

// Unified gather-GEMM:
//   C[m][n] = sum_kk A_gather[m][kk] * Bw[n*KK + kk]
// where m=(b,t): b = m>>LoutSh, t = m & (Lout-1)
//       kk=(c,kw): c = kk>>KwSh, kw = kk & (Kw-1)
//       A_gather = (0 <= i < L) ? A[b*Cc*L + c*L + i] : 0,  i = strd*t - pad + kw
// outMode 0: Cout[b*N*Lout + n*Lout + t] = relu?(acc+bias)  (NCH conv output)
// outMode 1: Cout[m*N + n] = acc                             (row-major scores)
__global__ __launch_bounds__(256) void gemm_conv(
    const float* __restrict__ A, const float* __restrict__ Bw,
    const float* __restrict__ bias, float* __restrict__ Cout,
    int M, int N, int KK, int Cc, int L, int Lout,
    int Kw, int strd, int pad, int relu, int outMode, int LoutSh, int KwSh)
{
    __shared__ float As[BK][BM];
    __shared__ float Bs[BK][BN];

    const int tid = threadIdx.x;
    const int tx = tid & 15;   // col group (n)
    const int ty = tid >> 4;   // row group (m)
    const int m0 = blockIdx.y * BM;
    const int n0 = blockIdx.x * BN;
    const int LoutM = Lout - 1;
    const int KwM = Kw - 1;

    float acc[8][8];
#pragma unroll
    for (int i = 0; i < 8; i++)
#pragma unroll
        for (int j = 0; j < 8; j++) acc[i][j] = 0.f;

    for (int k0 = 0; k0 < KK; k0 += BK) {
        // ---- stage A: BK*BM = 1024 elems, 4 scalar gathers per thread ----
#pragma unroll
        for (int l = 0; l < 4; l++) {
            int e = tid + 256 * l;
            int kk = e >> 7;
            int mm = e & 127;
            int m = m0 + mm;
            int kkg = k0 + kk;
            int c = kkg >> KwSh;
            int kw = kkg & KwM;
            int b = m >> LoutSh;
            int t = m & LoutM;
            int i = strd * t - pad + kw;
            float v = 0.f;
            if ((unsigned)i < (unsigned)L)
                v = A[(size_t)b * Cc * L + (size_t)c * L + i];
            As[kk][mm] = v;
        }
        // ---- stage B: each thread one float4 (row-major Bw) ----
        {
            int nn = tid >> 1;
            int part = tid & 1;
            const float4 bv = *reinterpret_cast<const float4*>(
                &Bw[(size_t)(n0 + nn) * KK + k0 + part * 4]);
            Bs[part * 4 + 0][nn] = bv.x;
            Bs[part * 4 + 1][nn] = bv.y;
            Bs[part * 4 + 2][nn] = bv.z;
            Bs[part * 4 + 3][nn] = bv.w;
        }
        __syncthreads();

#pragma unroll
        for (int kk = 0; kk < BK; kk++) {
            float4 a0 = *reinterpret_cast<const float4*>(&As[kk][ty * 4]);
            float4 a1 = *reinterpret_cast<const float4*>(&As[kk][64 + ty * 4]);
            float4 b0 = *reinterpret_cast<const float4*>(&Bs[kk][tx * 4]);
            float4 b1 = *reinterpret_cast<const float4*>(&Bs[kk][64 + tx * 4]);
            float a[8] = {a0.x, a0.y, a0.z, a0.w, a1.x, a1.y, a1.z, a1.w};
            float bb[8] = {b0.x, b0.y, b0.z, b0.w, b1.x, b1.y, b1.z, b1.w};
#pragma unroll
            for (int i = 0; i < 8; i++)
#pragma unroll
                for (int j = 0; j < 8; j++) acc[i][j] += a[i] * bb[j];
        }
        __syncthreads();
    }

    // ---- epilogue ----
    if (outMode == 0) {
        const int m_lo = m0 + ty * 4;
        const int m_hi = m0 + 64 + ty * 4;
        const int b_lo = m_lo >> LoutSh, t_lo = m_lo & LoutM;
        const int b_hi = m_hi >> LoutSh, t_hi = m_hi & LoutM;
#pragma unroll
        for (int j = 0; j < 8; j++) {
            int n = n0 + ((j < 4) ? (tx * 4 + j) : (64 + tx * 4 + (j - 4)));
            float bv = bias[n];
            float4 v, w;
            v.x = acc[0][j] + bv; v.y = acc[1][j] + bv;
            v.z = acc[2][j] + bv; v.w = acc[3][j] + bv;
            w.x = acc[4][j] + bv; w.y = acc[5][j] + bv;
            w.z = acc[6][j] + bv; w.w = acc[7][j] + bv;
            if (relu) {
                v.x = fmaxf(v.x, 0.f); v.y = fmaxf(v.y, 0.f);
                v.z = fmaxf(v.z, 0.f); v.w = fmaxf(v.w, 0.f);
                w.x = fmaxf(w.x, 0.f); w.y = fmaxf(w.y, 0.f);
                w.z = fmaxf(w.z, 0.f); w.w = fmaxf(w.w, 0.f);
            }
            *reinterpret_cast<float4*>(
                &Cout[((size_t)b_lo * N + n) * Lout + t_lo]) = v;
            *reinterpret_cast<float4*>(
                &Cout[((size_t)b_hi * N + n) * Lout + t_hi]) = w;
        }
    } else {
#pragma unroll
        for (int i = 0; i < 8; i++) {
            int m = m0 + ((i < 4) ? (ty * 4 + i) : (64 + ty * 4 + (i - 4)));
            float4 v = {acc[i][0], acc[i][1], acc[i][2], acc[i][3]};
            float4 w = {acc[i][4], acc[i][5], acc[i][6], acc[i][7]};
            *reinterpret_cast<float4*>(&Cout[(size_t)m * N + n0 + tx * 4]) = v;
            *reinterpret_cast<float4*>(&Cout[(size_t)m * N + n0 + 64 + tx * 4]) = w;
        }
    }
}

// ||codebook_n||^2, one wave per row
__global__ __launch_bounds__(64) void cb_norm(const float* __restrict__ cb,
                                              float* __restrict__ cn2) {
    int n = blockIdx.x;
    int lane = threadIdx.x;
    float s = 0.f;
    for (int d = lane; d < 512; d += 64) {
        float v = cb[(size_t)n * 512 + d];
        s += v * v;
    }
#pragma unroll
    for (int off = 32; off; off >>= 1) s += __shfl_down(s, off);
    if (lane == 0) cn2[n] = s;
}

// argmin over (cn2[n] - 2*S[r][n]); one wave per row, first-occurrence ties
__global__ __launch_bounds__(256) void argmin_k(const float* __restrict__ S,
                                                const float* __restrict__ cn2,
                                                float* __restrict__ idxf,
                                                int* __restrict__ idxi, int rows) {
    int wid = threadIdx.x >> 6;
    int lane = threadIdx.x & 63;
    int r = blockIdx.x * 4 + wid;
    if (r >= rows) return;
    const float* srow = S + (size_t)r * 1024;
    float best = INFINITY;
    int bi = 0;
#pragma unroll
    for (int it = 0; it < 4; it++) {
        int nb = it * 256 + lane * 4;
        float4 s4 = *reinterpret_cast<const float4*>(&srow[nb]);
        float4 c4 = *reinterpret_cast<const float4*>(&cn2[nb]);
        float v;
        v = c4.x - 2.f * s4.x; if (v < best) { best = v; bi = nb + 0; }
        v = c4.y - 2.f * s4.y; if (v < best) { best = v; bi = nb + 1; }
        v = c4.z - 2.f * s4.z; if (v < best) { best = v; bi = nb + 2; }
        v = c4.w - 2.f * s4.w; if (v < best) { best = v; bi = nb + 3; }
    }
#pragma unroll
    for (int off = 32; off; off >>= 1) {
        float ov = __shfl_down(best, off);
        int oi = __shfl_down(bi, off);
        if (ov < best || (ov == best && oi < bi)) { best = ov; bi = oi; }
    }
    if (lane == 0) {
        idxf[r] = (float)bi;
        idxi[r] = bi;
    }
}

// z_q[r][:] = codebook[idx[r]][:], one float4 per thread
__global__ __launch_bounds__(256) void gather_k(const int* __restrict__ idx,
                                                const float* __restrict__ cb,
                                                float* __restrict__ zq, int total4) {
    int g = blockIdx.x * 256 + threadIdx.x;
    if (g >= total4) return;
    int r = g >> 7;
    int d4 = g & 127;
    int id = idx[r];
    *reinterpret_cast<float4*>(&zq[(size_t)r * 512 + (size_t)d4 * 4]) =
        *reinterpret_cast<const float4*>(&cb[(size_t)id * 512 + (size_t)d4 * 4]);
}

extern "C" void kernel_launch(void* const* d_in, const int* in_sizes, int n_in,
                              void* d_out, int out_size, void* d_ws, size_t ws_size,
                              hipStream_t stream) {
    const float* x  = (const float*)d_in[0];  // (32, 256, 2048)
    const float* w1 = (const float*)d_in[1];  // (1024, 256, 4)
    const float* b1 = (const float*)d_in[2];  // (1024,)
    const float* w2 = (const float*)d_in[3];  // (512, 1024, 4)
    const float* b2 = (const float*)d_in[4];  // (512,)
    const float* cb = (const float*)d_in[5];  // (1024, 512)
    float* out = (float*)d_out;

    const int B = 32, Cin = 256, T = 2048, H = 1024, D = 512, Kc = 1024;
    const int T1 = 1024, T2 = 512;

    float* zq_out  = out;                                   // (B*T2, D) row-major
    float* idx_out = out + (size_t)B * T2 * D;              // (B*T2,) as float
    float* ze_out  = idx_out + (size_t)B * T2;              // (B, D, T2) NCH

    // batch chunking to fit workspace: need NB*H*T1 floats for h (+ cn2 + idx)
    const size_t per_b = (size_t)H * T1;  // 1M floats / batch
    int NB = 32;
    while (NB > 1 &&
           ((size_t)NB * per_b + 1024 + (size_t)NB * T2 + 64) * 4 > ws_size)
        NB >>= 1;

    float* h_ws = (float*)d_ws;           // NB*H*T1 floats (NCH)
    float* S_ws = (float*)d_ws;           // overlays h (h dead when S written)
    float* cn2  = h_ws + (size_t)NB * per_b;
    int* idx_ws = (int*)(cn2 + 1024);

    cb_norm<<<Kc, 64, 0, stream>>>(cb, cn2);

    for (int b0 = 0; b0 < B; b0 += NB) {
        int nb = (B - b0 < NB) ? (B - b0) : NB;

        // conv1 + relu: (nb,256,2048) -> h (nb,1024,1024)
        dim3 g1(H / BN, nb * T1 / BM);
        gemm_conv<<<g1, 256, 0, stream>>>(
            x + (size_t)b0 * Cin * T, w1, b1, h_ws,
            nb * T1, H, Cin * 4, Cin, T, T1,
            /*Kw*/4, /*strd*/2, /*pad*/1, /*relu*/1, /*mode*/0, /*LoutSh*/10, /*KwSh*/2);

        // conv2: h -> z_e (nb,512,512) written directly to output slot
        dim3 g2(D / BN, nb * T2 / BM);
        gemm_conv<<<g2, 256, 0, stream>>>(
            h_ws, w2, b2, ze_out + (size_t)b0 * D * T2,
            nb * T2, D, H * 4, H, T1, T2,
            4, 2, 1, /*relu*/0, /*mode*/0, /*LoutSh*/9, /*KwSh*/2);

        // scores: S[m][n] = z_flat[m] . cb[n]   (Kw=1,s=1,p=0 degenerate conv)
        dim3 g3(Kc / BN, nb * T2 / BM);
        gemm_conv<<<g3, 256, 0, stream>>>(
            ze_out + (size_t)b0 * D * T2, cb, nullptr, S_ws,
            nb * T2, Kc, D, D, T2, T2,
            1, 1, 0, /*relu*/0, /*mode*/1, /*LoutSh*/9, /*KwSh*/0);

        // argmin over (cn2 - 2S); write float idx to out, int idx to ws
        argmin_k<<<(nb * T2 + 3) / 4, 256, 0, stream>>>(
            S_ws, cn2, idx_out + (size_t)b0 * T2, idx_ws, nb * T2);

        // z_q gather
        int total4 = nb * T2 * D / 4;
        gather_k<<<(total4 + 255) / 256, 256, 0, stream>>>(
            idx_ws, cb, zq_out + (size_t)b0 * D * T2, total4);
    }
}

// Round 2
// 598.621 us; speedup vs baseline: 4.5495x; 4.5495x over previous
//
#include <hip/hip_runtime.h>
#include <hip/hip_bf16.h>

using f16x8 = __attribute__((ext_vector_type(8))) _Float16;
using f32x4 = __attribute__((ext_vector_type(4))) float;

union PackU { unsigned u; _Float16 h[2]; };

__device__ inline unsigned split_pack(float v) {
    _Float16 h0 = (_Float16)v;
    float r = (v - (float)h0) * 4096.0f;   // exact; scaled residual stays fp16-normal
    PackU p; p.h[0] = h0; p.h[1] = (_Float16)r;
    return p.u;
}

// fp32 -> packed {f16 hi, f16 lo*4096} planes
__global__ __launch_bounds__(256) void split_kernel(const float* __restrict__ src,
                                                    unsigned* __restrict__ dst, int n4) {
    int g = blockIdx.x * 256 + threadIdx.x;
    if (g >= n4) return;
    float4 v = reinterpret_cast<const float4*>(src)[g];
    uint4 o;
    o.x = split_pack(v.x); o.y = split_pack(v.y);
    o.z = split_pack(v.z); o.w = split_pack(v.w);
    reinterpret_cast<uint4*>(dst)[g] = o;
}

#define BMt 128
#define BNt 128
#define BKt 32

// Unified split-fp16 MFMA gather-GEMM.
// C[m][n] = sum_kk A[m][kk] * B[n][kk]   (B row-major [N][KK])
// gather: A[m][kk] = Ap[b][c][i], kk=(c,kw), i=2t-1+kw, m=(b,t)
// mode 0: OutP[b][n][Lout]+t = split_pack(relu(acc+bias))      (conv1 -> hp)
// mode 1: OutF NCH fp32 (+bias) AND OutP[m][N] packed          (conv2 -> ze, zp)
// mode 2: OutF[m][N] fp32                                      (scores)
__global__ __launch_bounds__(256, 2) void mfma_gemm(
    const unsigned* __restrict__ Ap, const unsigned* __restrict__ Bp,
    const float* __restrict__ bias,
    unsigned* __restrict__ OutP, float* __restrict__ OutF,
    int M, int N, int KK, int Cc, int L, int Lout, int LoutSh,
    int gatherMode, int mode)
{
    __shared__ uint4 As4[BMt * 8];   // [row][chunk] chunks: plane*4 + k/8, XOR-swizzled
    __shared__ uint4 Bs4[BNt * 8];

    const int tid = threadIdx.x;
    const int m0 = blockIdx.y * BMt;
    const int n0 = blockIdx.x * BNt;

    // staging mapping: thread -> (row, k-half)
    const int srow = tid >> 1;
    const int kh = tid & 1;
    const int am = m0 + srow;
    const int ab = am >> LoutSh;
    const int at = am & (Lout - 1);
    const unsigned* aprow = Ap + (size_t)ab * Cc * L;
    const int ai0 = 2 * at - 1;
    const unsigned* adir = Ap + (size_t)am * KK;
    const unsigned* brow = Bp + (size_t)(n0 + srow) * KK;

    // wave mapping
    const int lane = tid & 63;
    const int wv = tid >> 6;
    const int wr = wv >> 1, wc = wv & 1;
    const int l15 = lane & 15, lq = lane >> 4;

    f32x4 acc0[4][4] = {{{0.f}}};
    f32x4 acc1[4][4] = {{{0.f}}};

    for (int k0 = 0; k0 < KK; k0 += BKt) {
        uint4 pa[4], pb[4];
        if (gatherMode) {
            int cbase = (k0 >> 2) + kh * 4;
#pragma unroll
            for (int cl = 0; cl < 4; cl++) {
                const unsigned* base = aprow + (size_t)(cbase + cl) * L;
                unsigned q0 = 0, q3 = 0;
                if (ai0 >= 0) q0 = base[ai0];           // only t==0 pads
                unsigned q1 = base[ai0 + 1];            // always in [0, L-2]
                unsigned q2 = base[ai0 + 2];            // always in [1, L-1]
                if (ai0 + 3 < L) q3 = base[ai0 + 3];    // only t==Lout-1 pads
                pa[cl].x = q0; pa[cl].y = q1; pa[cl].z = q2; pa[cl].w = q3;
            }
        } else {
            const uint4* s = reinterpret_cast<const uint4*>(adir + k0 + kh * 16);
            pa[0] = s[0]; pa[1] = s[1]; pa[2] = s[2]; pa[3] = s[3];
        }
        {
            const uint4* s = reinterpret_cast<const uint4*>(brow + k0 + kh * 16);
            pb[0] = s[0]; pb[1] = s[1]; pb[2] = s[2]; pb[3] = s[3];
        }

        __syncthreads();   // previous tile's reads complete before overwrite

        // split planes and write (16 elems = 2 chunks per plane)
#pragma unroll
        for (int ch = 0; ch < 2; ch++) {
            uint4 w0, w1, v0, v1;
            unsigned* W0 = (unsigned*)&w0; unsigned* W1 = (unsigned*)&w1;
            unsigned* V0 = (unsigned*)&v0; unsigned* V1 = (unsigned*)&v1;
#pragma unroll
            for (int j = 0; j < 4; j++) {
                int e0 = ch * 8 + 2 * j, e1 = e0 + 1;
                unsigned lo = ((const unsigned*)&pa[e0 >> 2])[e0 & 3];
                unsigned hi = ((const unsigned*)&pa[e1 >> 2])[e1 & 3];
                W0[j] = (lo & 0xffffu) | (hi << 16);
                W1[j] = (lo >> 16) | (hi & 0xffff0000u);
                lo = ((const unsigned*)&pb[e0 >> 2])[e0 & 3];
                hi = ((const unsigned*)&pb[e1 >> 2])[e1 & 3];
                V0[j] = (lo & 0xffffu) | (hi << 16);
                V1[j] = (lo >> 16) | (hi & 0xffff0000u);
            }
            int kc = kh * 2 + ch;
            int sw = srow & 7;
            As4[srow * 8 + ((kc) ^ sw)] = w0;
            As4[srow * 8 + ((4 + kc) ^ sw)] = w1;
            Bs4[srow * 8 + ((kc) ^ sw)] = v0;
            Bs4[srow * 8 + ((4 + kc) ^ sw)] = v1;
        }

        __syncthreads();

        f16x8 a0f[4], a1f[4], b0f[4], b1f[4];
#pragma unroll
        for (int mf = 0; mf < 4; mf++) {
            int row = wr * 64 + mf * 16 + l15;
            int sw = row & 7;
            a0f[mf] = *reinterpret_cast<const f16x8*>(&As4[row * 8 + (lq ^ sw)]);
            a1f[mf] = *reinterpret_cast<const f16x8*>(&As4[row * 8 + ((4 + lq) ^ sw)]);
        }
#pragma unroll
        for (int nf = 0; nf < 4; nf++) {
            int row = wc * 64 + nf * 16 + l15;
            int sw = row & 7;
            b0f[nf] = *reinterpret_cast<const f16x8*>(&Bs4[row * 8 + (lq ^ sw)]);
            b1f[nf] = *reinterpret_cast<const f16x8*>(&Bs4[row * 8 + ((4 + lq) ^ sw)]);
        }
#pragma unroll
        for (int mf = 0; mf < 4; mf++)
#pragma unroll
            for (int nf = 0; nf < 4; nf++) {
                acc0[mf][nf] = __builtin_amdgcn_mfma_f32_16x16x32_f16(
                    a0f[mf], b0f[nf], acc0[mf][nf], 0, 0, 0);
                acc1[mf][nf] = __builtin_amdgcn_mfma_f32_16x16x32_f16(
                    a0f[mf], b1f[nf], acc1[mf][nf], 0, 0, 0);
                acc1[mf][nf] = __builtin_amdgcn_mfma_f32_16x16x32_f16(
                    a1f[mf], b0f[nf], acc1[mf][nf], 0, 0, 0);
            }
    }

    const float s12 = 1.0f / 4096.0f;
    const int LoutM = Lout - 1;

    if (mode == 2) {
#pragma unroll
        for (int mf = 0; mf < 4; mf++) {
            int mb = m0 + wr * 64 + mf * 16 + lq * 4;
#pragma unroll
            for (int nf = 0; nf < 4; nf++) {
                int n = n0 + wc * 64 + nf * 16 + l15;
#pragma unroll
                for (int r = 0; r < 4; r++) {
                    float v = acc0[mf][nf][r] + acc1[mf][nf][r] * s12;
                    OutF[(size_t)(mb + r) * N + n] = v;
                }
            }
        }
    } else if (mode == 0) {
#pragma unroll
        for (int mf = 0; mf < 4; mf++) {
            int mb = m0 + wr * 64 + mf * 16 + lq * 4;
            int b = mb >> LoutSh, t = mb & LoutM;
#pragma unroll
            for (int nf = 0; nf < 4; nf++) {
                int n = n0 + wc * 64 + nf * 16 + l15;
                float bv = bias[n];
                uint4 o;
                unsigned* O = (unsigned*)&o;
#pragma unroll
                for (int r = 0; r < 4; r++) {
                    float v = acc0[mf][nf][r] + acc1[mf][nf][r] * s12 + bv;
                    v = fmaxf(v, 0.f);
                    O[r] = split_pack(v);
                }
                *reinterpret_cast<uint4*>(&OutP[((size_t)b * N + n) * Lout + t]) = o;
            }
        }
    } else {  // mode 1
#pragma unroll
        for (int mf = 0; mf < 4; mf++) {
            int mb = m0 + wr * 64 + mf * 16 + lq * 4;
            int b = mb >> LoutSh, t = mb & LoutM;
#pragma unroll
            for (int nf = 0; nf < 4; nf++) {
                int n = n0 + wc * 64 + nf * 16 + l15;
                float bv = bias[n];
                float4 f;
                unsigned O[4];
#pragma unroll
                for (int r = 0; r < 4; r++) {
                    float v = acc0[mf][nf][r] + acc1[mf][nf][r] * s12 + bv;
                    ((float*)&f)[r] = v;
                    O[r] = split_pack(v);
                }
                *reinterpret_cast<float4*>(&OutF[((size_t)b * N + n) * Lout + t]) = f;
#pragma unroll
                for (int r = 0; r < 4; r++)
                    OutP[(size_t)(mb + r) * N + n] = O[r];
            }
        }
    }
}

// ||codebook_n||^2, one wave per row (fp32 exact)
__global__ __launch_bounds__(64) void cb_norm(const float* __restrict__ cb,
                                              float* __restrict__ cn2) {
    int n = blockIdx.x;
    int lane = threadIdx.x;
    float s = 0.f;
    for (int d = lane; d < 512; d += 64) {
        float v = cb[(size_t)n * 512 + d];
        s += v * v;
    }
#pragma unroll
    for (int off = 32; off; off >>= 1) s += __shfl_down(s, off);
    if (lane == 0) cn2[n] = s;
}

// argmin over (cn2[n] - 2*S[r][n]); one wave per row, first-occurrence ties
__global__ __launch_bounds__(256) void argmin_k(const float* __restrict__ S,
                                                const float* __restrict__ cn2,
                                                float* __restrict__ idxf,
                                                int* __restrict__ idxi, int rows) {
    int wid = threadIdx.x >> 6;
    int lane = threadIdx.x & 63;
    int r = blockIdx.x * 4 + wid;
    if (r >= rows) return;
    const float* srow = S + (size_t)r * 1024;
    float best = INFINITY;
    int bi = 0;
#pragma unroll
    for (int it = 0; it < 4; it++) {
        int nb = it * 256 + lane * 4;
        float4 s4 = *reinterpret_cast<const float4*>(&srow[nb]);
        float4 c4 = *reinterpret_cast<const float4*>(&cn2[nb]);
        float v;
        v = c4.x - 2.f * s4.x; if (v < best) { best = v; bi = nb + 0; }
        v = c4.y - 2.f * s4.y; if (v < best) { best = v; bi = nb + 1; }
        v = c4.z - 2.f * s4.z; if (v < best) { best = v; bi = nb + 2; }
        v = c4.w - 2.f * s4.w; if (v < best) { best = v; bi = nb + 3; }
    }
#pragma unroll
    for (int off = 32; off; off >>= 1) {
        float ov = __shfl_down(best, off);
        int oi = __shfl_down(bi, off);
        if (ov < best || (ov == best && oi < bi)) { best = ov; bi = oi; }
    }
    if (lane == 0) {
        idxf[r] = (float)bi;
        idxi[r] = bi;
    }
}

// z_q[r][:] = codebook[idx[r]][:]
__global__ __launch_bounds__(256) void gather_k(const int* __restrict__ idx,
                                                const float* __restrict__ cb,
                                                float* __restrict__ zq, int total4) {
    int g = blockIdx.x * 256 + threadIdx.x;
    if (g >= total4) return;
    int r = g >> 7;
    int d4 = g & 127;
    int id = idx[r];
    *reinterpret_cast<float4*>(&zq[(size_t)r * 512 + (size_t)d4 * 4]) =
        *reinterpret_cast<const float4*>(&cb[(size_t)id * 512 + (size_t)d4 * 4]);
}

extern "C" void kernel_launch(void* const* d_in, const int* in_sizes, int n_in,
                              void* d_out, int out_size, void* d_ws, size_t ws_size,
                              hipStream_t stream) {
    const float* x  = (const float*)d_in[0];  // (32, 256, 2048)
    const float* w1 = (const float*)d_in[1];  // (1024, 256, 4) = [n][kk]
    const float* b1 = (const float*)d_in[2];
    const float* w2 = (const float*)d_in[3];  // (512, 1024, 4)
    const float* b2 = (const float*)d_in[4];
    const float* cb = (const float*)d_in[5];  // (1024, 512)
    float* out = (float*)d_out;

    const int B = 32, Cin = 256, T = 2048, H = 1024, D = 512, Kc = 1024;
    const int T1 = 1024, T2 = 512;

    float* zq_out  = out;                       // (B*T2, D)
    float* idx_out = out + (size_t)B * T2 * D;  // (B*T2,)
    float* ze_out  = idx_out + (size_t)B * T2;  // (B, D, T2)

    // ws layout (u32 units)
    unsigned* w1p = (unsigned*)d_ws;                       // H*Cin*4
    unsigned* w2p = w1p + (size_t)H * Cin * 4;             // D*H*4
    unsigned* cbp = w2p + (size_t)D * H * 4;               // Kc*D
    float* cn2    = (float*)(cbp + (size_t)Kc * D);        // Kc
    int* idx_ws   = (int*)(cn2 + Kc);                      // B*T2
    unsigned* dyn = (unsigned*)(idx_ws + B * T2);

    size_t fixed_u32 = (size_t)H * Cin * 4 + (size_t)D * H * 4 + (size_t)Kc * D
                       + Kc + (size_t)B * T2 + 256;
    int NB = 32;
    while (NB > 1 &&
           (fixed_u32 + (size_t)NB * ((size_t)Cin * T + (size_t)H * T1 + (size_t)T2 * D))
               * 4 > ws_size)
        NB >>= 1;

    unsigned* xp = dyn;
    unsigned* hp = xp + (size_t)NB * Cin * T;
    unsigned* zp = hp + (size_t)NB * H * T1;
    float* S = (float*)hp;   // overlays hp (dead when scores run)

    split_kernel<<<(H * Cin * 4 / 4 + 255) / 256, 256, 0, stream>>>(w1, w1p, H * Cin * 4 / 4);
    split_kernel<<<(D * H * 4 / 4 + 255) / 256, 256, 0, stream>>>(w2, w2p, D * H * 4 / 4);
    split_kernel<<<(Kc * D / 4 + 255) / 256, 256, 0, stream>>>(cb, cbp, Kc * D / 4);
    cb_norm<<<Kc, 64, 0, stream>>>(cb, cn2);

    for (int b0 = 0; b0 < B; b0 += NB) {
        int nb = (B - b0 < NB) ? (B - b0) : NB;

        split_kernel<<<(nb * Cin * T / 4 + 255) / 256, 256, 0, stream>>>(
            x + (size_t)b0 * Cin * T, xp, nb * Cin * T / 4);

        // conv1 + relu -> hp (packed NCH)
        mfma_gemm<<<dim3(H / BNt, nb * T1 / BMt), 256, 0, stream>>>(
            xp, w1p, b1, hp, nullptr,
            nb * T1, H, Cin * 4, Cin, T, T1, /*LoutSh*/10, /*gather*/1, /*mode*/0);

        // conv2 -> ze (fp32 NCH) + zp (packed [m][D])
        mfma_gemm<<<dim3(D / BNt, nb * T2 / BMt), 256, 0, stream>>>(
            hp, w2p, b2, zp, ze_out + (size_t)b0 * D * T2,
            nb * T2, D, H * 4, H, T1, T2, /*LoutSh*/9, /*gather*/1, /*mode*/1);

        // scores S[m][n] = z.cb
        mfma_gemm<<<dim3(Kc / BNt, nb * T2 / BMt), 256, 0, stream>>>(
            zp, cbp, nullptr, nullptr, S,
            nb * T2, Kc, D, D, T2, T2, /*LoutSh*/9, /*gather*/0, /*mode*/2);

        argmin_k<<<(nb * T2 + 3) / 4, 256, 0, stream>>>(
            S, cn2, idx_out + (size_t)b0 * T2, idx_ws, nb * T2);

        gather_k<<<(nb * T2 * D / 4 + 255) / 256, 256, 0, stream>>>(
            idx_ws, cb, zq_out + (size_t)b0 * T2 * D, nb * T2 * D / 4);
    }
}